// Round 1
// baseline (464.291 us; speedup 1.0000x reference)
//
#include <hip/hip_runtime.h>
#include <hip/hip_bf16.h>

#define BATCH 32
#define CIN   256
#define OCH   256
#define HW    56
#define PW    58
#define PAREA (PW*PW)   /* 3364 */
#define PLANE (HW*HW)   /* 3136 */

typedef float float4v __attribute__((ext_vector_type(4)));
typedef short short8  __attribute__((ext_vector_type(8)));

__device__ __forceinline__ unsigned short f2bf(float f) {
  union { float f; unsigned u; } v; v.f = f;
  unsigned r = v.u + 0x7fffu + ((v.u >> 16) & 1u);
  return (unsigned short)(r >> 16);
}

// ---------------- Kernel 1: adaptive avg+max pool (56x56 -> 5x5) ----------------
__global__ __launch_bounds__(256) void pool_kernel(const float* __restrict__ x,
                                                   float* __restrict__ avgp,
                                                   float* __restrict__ maxp) {
  __shared__ float plane[PLANE];
  int bc = blockIdx.x;  // b*256 + c
  const float* src = x + (size_t)bc * PLANE;
  for (int e = threadIdx.x; e < PLANE; e += 256) plane[e] = src[e];
  __syncthreads();
  if (threadIdx.x < 25) {
    int i = threadIdx.x / 5, j = threadIdx.x % 5;
    int r0 = (i * HW) / 5, r1 = ((i + 1) * HW + 4) / 5;
    int c0 = (j * HW) / 5, c1 = ((j + 1) * HW + 4) / 5;
    float s = 0.f, m = -1e30f;
    for (int r = r0; r < r1; ++r)
      for (int c = c0; c < c1; ++c) {
        float v = plane[r * HW + c];
        s += v; m = fmaxf(m, v);
      }
    avgp[(size_t)bc * 25 + threadIdx.x] = s / (float)((r1 - r0) * (c1 - c0));
    maxp[(size_t)bc * 25 + threadIdx.x] = m;
  }
}

// ---------------- Kernel 2: dynamic weight computation -> Wbf[b][r][oc][ic] bf16 ----
__global__ __launch_bounds__(256) void wcalc_kernel(
    const float* __restrict__ avgp, const float* __restrict__ maxp,
    const float* __restrict__ w1, const float* __restrict__ b1,
    const float* __restrict__ w2, const float* __restrict__ b2,
    const float* __restrict__ watt, const float* __restrict__ batt,
    unsigned short* __restrict__ Wbf) {
  int blk = blockIdx.x;
  int oc = blk & 255, b = blk >> 8;
  __shared__ float s_avg[25], s_max[25], s_w1[9], s_wgt1[9];
  int tid = threadIdx.x;
  size_t base = ((size_t)b * 256 + oc) * 25;
  if (tid < 25) { s_avg[tid] = avgp[base + tid]; s_max[tid] = maxp[base + tid]; }
  if (tid >= 32 && tid < 41) s_w1[tid - 32] = w1[oc * 9 + (tid - 32)];
  __syncthreads();
  if (tid < 9) {
    int ky = tid / 3, kx = tid % 3;
    float acc = b1[oc];
    for (int u = 0; u < 3; ++u)
      for (int v = 0; v < 3; ++v)
        acc += s_avg[(ky + u) * 5 + kx + v] * s_w1[u * 3 + v];
    s_wgt1[tid] = fmaxf(acc, 0.f);
  }
  __syncthreads();
  int ic = tid;
  size_t g = (size_t)oc * 256 + ic;
  float wa[9];
#pragma unroll
  for (int r = 0; r < 9; ++r) wa[r] = watt[g * 9 + r];
  float ba = batt[g], w2v = w2[g], b2v = b2[g];
#pragma unroll
  for (int r = 0; r < 9; ++r) {
    int ky = r / 3, kx = r % 3;
    float s = ba;
#pragma unroll
    for (int u = 0; u < 3; ++u)
#pragma unroll
      for (int v = 0; v < 3; ++v)
        s += s_max[(ky + u) * 5 + kx + v] * wa[u * 3 + v];
    float att = 1.f / (1.f + __expf(-s));
    float wv = (s_wgt1[r] * w2v + b2v) * att;
    Wbf[(((size_t)b * 9 + r) * 256 + oc) * 256 + ic] = f2bf(wv);
  }
}

// ---------------- Kernel 3a: zero the padded border of xp ----------------
__global__ __launch_bounds__(256) void border_kernel(unsigned short* __restrict__ xp) {
  int bid = blockIdx.x;           // 32 * 228
  int b = bid / 228, bi = bid % 228;
  int pos;
  if (bi < 58)       pos = bi;
  else if (bi < 116) pos = 57 * PW + (bi - 58);
  else if (bi < 172) pos = (bi - 116 + 1) * PW;
  else               pos = (bi - 172 + 1) * PW + 57;
  xp[((size_t)b * PAREA + pos) * 256 + threadIdx.x] = 0;
}

// ---------------- Kernel 3b: x fp32 [b][ic][y][x] -> xp bf16 [b][pos][ic] --------
__global__ __launch_bounds__(256) void xprep_kernel(const float* __restrict__ x,
                                                    unsigned short* __restrict__ xp) {
  // block = (b, icb of 64, row y)
  int bid = blockIdx.x;
  int y = bid % 56; int t2 = bid / 56; int icb = t2 & 3; int b = t2 >> 2;
  __shared__ float tr[56][65];
  for (int e = threadIdx.x; e < 56 * 64; e += 256) {
    int icl = e / 56, col = e % 56;
    tr[col][icl] = x[((size_t)(b * 256 + icb * 64 + icl)) * PLANE + y * HW + col];
  }
  __syncthreads();
  for (int e = threadIdx.x; e < 448; e += 256) {
    int col = e >> 3, c8 = e & 7;
    short8 v;
#pragma unroll
    for (int k = 0; k < 8; ++k) v[k] = (short)f2bf(tr[col][c8 * 8 + k]);
    size_t dst = ((size_t)b * PAREA + (size_t)(y + 1) * PW + (col + 1)) * 256 + icb * 64 + c8 * 8;
    *(short8*)&xp[dst] = v;
  }
}

// ---------------- Kernel 4: dynamic conv via MFMA -------------------------------
// block: 128 oc x (4 rows x 56) pixels, grid = 32b * 2ocb * 14rt = 896
__global__ __launch_bounds__(256, 2) void conv_kernel(
    const unsigned short* __restrict__ xp,
    const unsigned short* __restrict__ Wbf,
    float* __restrict__ out) {
  __shared__ unsigned short bpl[348 * 32];  // [pos 6*58][ic 32]
  __shared__ unsigned short apl[128 * 32];  // [oc][ic 32]

  int bid = blockIdx.x;
  int rt = bid % 14; int t2 = bid / 14; int ocb = t2 & 1; int b = t2 >> 1;
  int y0 = rt * 4;
  int tid = threadIdx.x;
  int lane = tid & 63, w = tid >> 6;
  int mw = w & 1, nw = w >> 1;     // 2 M-waves x 2 N-waves
  int quad = lane >> 4, l16 = lane & 15;

  int basepos[7];
#pragma unroll
  for (int nt = 0; nt < 7; ++nt) {
    int n = nw * 112 + nt * 16 + l16;
    basepos[nt] = (n / 56) * PW + (n % 56);
  }

  float4v acc[4][7];
#pragma unroll
  for (int mt = 0; mt < 4; ++mt)
#pragma unroll
    for (int nt = 0; nt < 7; ++nt)
      acc[mt][nt] = (float4v){0.f, 0.f, 0.f, 0.f};

  const size_t xbase = ((size_t)b * PAREA + (size_t)y0 * PW) * 256;

  for (int icb = 0; icb < 8; ++icb) {
    __syncthreads();   // previous iter's bpl reads done
    // stage B-plane: 6 rows x 58 cols x 32 ic = 1392 chunks of 8 bf16
    for (int e = tid; e < 1392; e += 256) {
      int c = e & 3, p = e >> 2;
      *(short8*)&bpl[p * 32 + c * 8] =
          *(const short8*)&xp[xbase + (size_t)p * 256 + icb * 32 + c * 8];
    }
    for (int r = 0; r < 9; ++r) {
      __syncthreads();  // bpl visible (r=0) / previous apl reads done (r>0)
      const size_t wbase = (((size_t)b * 9 + r) * 256 + ocb * 128) * 256 + icb * 32;
      for (int e = tid; e < 512; e += 256) {
        int c = e & 3, oc = e >> 2;
        *(short8*)&apl[oc * 32 + c * 8] =
            *(const short8*)&Wbf[wbase + (size_t)oc * 256 + c * 8];
      }
      __syncthreads();
      int ky = r / 3, kx = r - ky * 3;
      int poff = (ky * PW + kx) * 32;
      short8 bfrag[7];
#pragma unroll
      for (int nt = 0; nt < 7; ++nt)
        bfrag[nt] = *(const short8*)&bpl[basepos[nt] * 32 + poff + quad * 8];
#pragma unroll
      for (int mt = 0; mt < 4; ++mt) {
        short8 afrag = *(const short8*)&apl[(mw * 64 + mt * 16 + l16) * 32 + quad * 8];
#pragma unroll
        for (int nt = 0; nt < 7; ++nt)
          acc[mt][nt] = __builtin_amdgcn_mfma_f32_16x16x32_bf16(afrag, bfrag[nt], acc[mt][nt], 0, 0, 0);
      }
    }
  }

  // epilogue: D row = quad*4+reg (m), col = l16 (n)
#pragma unroll
  for (int mt = 0; mt < 4; ++mt) {
    int m = ocb * 128 + mw * 64 + mt * 16 + quad * 4;
#pragma unroll
    for (int nt = 0; nt < 7; ++nt) {
      int n = nw * 112 + nt * 16 + l16;
      int yy = y0 + n / 56, xx = n % 56;
      size_t o = (((size_t)b * 256 + m) * 56 + yy) * 56 + xx;
#pragma unroll
      for (int reg = 0; reg < 4; ++reg)
        out[o + (size_t)reg * PLANE] = acc[mt][nt][reg];
    }
  }
}

extern "C" void kernel_launch(void* const* d_in, const int* in_sizes, int n_in,
                              void* d_out, int out_size, void* d_ws, size_t ws_size,
                              hipStream_t stream) {
  const float* x    = (const float*)d_in[0];
  const float* w1   = (const float*)d_in[1];
  const float* b1   = (const float*)d_in[2];
  const float* w2   = (const float*)d_in[3];
  const float* b2   = (const float*)d_in[4];
  const float* watt = (const float*)d_in[5];
  const float* batt = (const float*)d_in[6];
  float* out = (float*)d_out;

  float* avgp = (float*)d_ws;                          // 204800 f32
  float* maxp = avgp + 204800;                         // 204800 f32
  unsigned short* Wbf = (unsigned short*)(maxp + 204800);  // 32*9*256*256 bf16
  unsigned short* xp  = Wbf + (size_t)32 * 9 * 256 * 256;  // 32*3364*256 bf16

  pool_kernel<<<BATCH * CIN, 256, 0, stream>>>(x, avgp, maxp);
  wcalc_kernel<<<BATCH * OCH, 256, 0, stream>>>(avgp, maxp, w1, b1, w2, b2, watt, batt, Wbf);
  border_kernel<<<BATCH * 228, 256, 0, stream>>>(xp);
  xprep_kernel<<<BATCH * 4 * 56, 256, 0, stream>>>(x, xp);
  conv_kernel<<<BATCH * 2 * 14, 256, 0, stream>>>(xp, Wbf, out);
}